// Round 3
// baseline (6431.454 us; speedup 1.0000x reference)
//
#include <hip/hip_runtime.h>
#include <stdint.h>

// Problem constants (fixed by the reference)
#define NROUTE 2
#define NB 4
#define NT 2048
#define ND 1024
#define NKQK 512
#define NVV 8192
#define NTOPK 8
#define NBT (NB*NT)   // 8192 tokens

typedef short short8 __attribute__((ext_vector_type(8)));
typedef float floatx4 __attribute__((ext_vector_type(4)));

// Persistent device scratch (module-scope; fully rewritten every call).
__device__ unsigned long long g_enc_q[NROUTE*NBT];
__device__ unsigned long long g_enc_k[NROUTE*NBT];
__device__ unsigned long long g_enc_v[NROUTE*NBT];
__device__ int g_tab_idx[NROUTE*NB*NKQK*NTOPK];
__device__ int g_tab_val[NROUTE*NB*NKQK*NTOPK];

// bf16 triple-split of inputs: value = h + m + l (each RNE bf16).
__device__ unsigned short g_xh[NBT*ND],        g_xm[NBT*ND],        g_xl[NBT*ND];
__device__ unsigned short g_wqh[NROUTE*NKQK*ND], g_wqm[NROUTE*NKQK*ND], g_wql[NROUTE*NKQK*ND];
__device__ unsigned short g_wkh[NROUTE*NKQK*ND], g_wkm[NROUTE*NKQK*ND], g_wkl[NROUTE*NKQK*ND];
__device__ unsigned short g_wvh[NROUTE*NVV*ND],  g_wvm[NROUTE*NVV*ND],  g_wvl[NROUTE*NVV*ND];

__global__ __launch_bounds__(256) void zero_enc_kernel() {
  int i = blockIdx.x * 256 + threadIdx.x;
  if (i < NROUTE*NBT) { g_enc_q[i] = 0ull; g_enc_k[i] = 0ull; g_enc_v[i] = 0ull; }
}

__device__ __forceinline__ unsigned short rne_bf16(float f) {
  unsigned u = __float_as_uint(f);
  return (unsigned short)((u + 0x7FFFu + ((u >> 16) & 1u)) >> 16);
}

// which: 0=x, 1=Wq, 2=Wk, 3=Wv.  n4 = element_count/4.
// x = h + m + l with h=RNE(x), m=RNE(x-h), l=RNE(x-h-m); both residual
// subtractions are exact (Sterbenz), dropped tail <= 2^-26 relative.
__global__ __launch_bounds__(256) void split_kernel(
    const float* __restrict__ src, int which, int n4)
{
  unsigned short* __restrict__ h = (which==0)?g_xh:(which==1)?g_wqh:(which==2)?g_wkh:g_wvh;
  unsigned short* __restrict__ m = (which==0)?g_xm:(which==1)?g_wqm:(which==2)?g_wkm:g_wvm;
  unsigned short* __restrict__ l = (which==0)?g_xl:(which==1)?g_wql:(which==2)?g_wkl:g_wvl;
  int stride = gridDim.x * 256;
  for (int i = blockIdx.x * 256 + threadIdx.x; i < n4; i += stride) {
    float4 v = ((const float4*)src)[i];
    float vv[4] = {v.x, v.y, v.z, v.w};
    unsigned short hb[4], mb[4], lb[4];
    #pragma unroll
    for (int j = 0; j < 4; j++) {
      float x = vv[j];
      unsigned short hh = rne_bf16(x);
      float hf = __uint_as_float((unsigned)hh << 16);
      float r1 = x - hf;
      unsigned short mm = rne_bf16(r1);
      float mf = __uint_as_float((unsigned)mm << 16);
      float r2 = r1 - mf;
      hb[j] = hh; mb[j] = mm; lb[j] = rne_bf16(r2);
    }
    ushort4 ho = make_ushort4(hb[0], hb[1], hb[2], hb[3]);
    ushort4 mo = make_ushort4(mb[0], mb[1], mb[2], mb[3]);
    ushort4 lo = make_ushort4(lb[0], lb[1], lb[2], lb[3]);
    ((ushort4*)h)[i] = ho; ((ushort4*)m)[i] = mo; ((ushort4*)l)[i] = lo;
  }
}

// MFMA GEMM + argmax.  scores[token][v] = sum_d x[t][d]*W[v][d], computed as
// 6 bf16 MFMA products (hh,hm,mh,hl,lh,mm) in fp32 accumulators.
// 128x128 tile, BK=32, 4 waves (2x2), wave = 64x64 via 4x4 16x16x32 frags.
// LDS 48KB: A levels h/m/l at ushort base L*4096, B at 12288 + L*4096,
// each level [row 0..127][k 0..31] row-major (row stride 32 ushorts).
// Fragment reads cover a full contiguous 1KB per wave -> conflict-free.
// Cross-block argmax merge via 64-bit atomicMax of monotone encoding
// (score_bits<<32)|~idx  (max score, then smallest index on ties).
__global__ __launch_bounds__(256) void mfma_argmax_kernel(int V, int sel)
{
  __shared__ unsigned short lds[24576];   // 48 KB
  unsigned long long* enc = (sel==0)?g_enc_q:(sel==1)?g_enc_k:g_enc_v;
  const unsigned short* __restrict__ Bh = (sel==0)?g_wqh:(sel==1)?g_wkh:g_wvh;
  const unsigned short* __restrict__ Bm = (sel==0)?g_wqm:(sel==1)?g_wkm:g_wvm;
  const unsigned short* __restrict__ Bl = (sel==0)?g_wql:(sel==1)?g_wkl:g_wvl;

  const int m     = blockIdx.z;
  const int tbase = blockIdx.x * 128;
  const int vbase = blockIdx.y * 128;
  const int tid   = threadIdx.x;
  const int lane  = tid & 63;
  const int wid   = tid >> 6;
  const int wr    = wid >> 1, wc = wid & 1;

  // Staging: 12 rounds x 256 threads x 16B = 48KB.  Round r fills LDS bytes
  // [r*4096, r*4096+4096); region r>>1 in {xh,xm,xl,Bh,Bm,Bl}.
  const unsigned short* srcs[12];
  #pragma unroll
  for (int r = 0; r < 12; r++) {
    const int region = r >> 1;                       // compile-time per r
    const int row  = ((r & 1) << 6) + (tid >> 2);    // 0..127
    const int koff = (tid & 3) << 3;                 // 0,8,16,24
    const unsigned short* base =
        (region==0)?g_xh:(region==1)?g_xm:(region==2)?g_xl:
        (region==3)?Bh:(region==4)?Bm:Bl;
    size_t ridx = (region < 3) ? (size_t)(tbase + row)
                               : ((size_t)m * (size_t)V + vbase + row);
    srcs[r] = base + ridx * ND + koff;
  }

  uint4 st[12];
  #pragma unroll
  for (int r = 0; r < 12; r++) st[r] = *(const uint4*)(srcs[r]);

  floatx4 acc[4][4];
  #pragma unroll
  for (int i = 0; i < 4; i++)
    #pragma unroll
    for (int j = 0; j < 4; j++) acc[i][j] = (floatx4){0.f, 0.f, 0.f, 0.f};

  for (int kt = 0; kt < ND/32; kt++) {
    __syncthreads();                       // previous tile fully consumed
    #pragma unroll
    for (int r = 0; r < 12; r++)
      *(uint4*)&lds[r*2048 + tid*8] = st[r];
    __syncthreads();                       // tile visible
    if (kt < ND/32 - 1) {
      #pragma unroll
      for (int r = 0; r < 12; r++)         // prefetch next tile: latency
        st[r] = *(const uint4*)(srcs[r] + (kt+1)*32);  // hides under MFMA
    }

    short8 A[3][4];
    #pragma unroll
    for (int L = 0; L < 3; L++)
      #pragma unroll
      for (int fr = 0; fr < 4; fr++) {
        int off = L*4096 + (wr*64 + fr*16 + (lane & 15))*32 + ((lane >> 4) << 3);
        A[L][fr] = *(const short8*)&lds[off];
      }
    #pragma unroll
    for (int fc = 0; fc < 4; fc++) {
      int cb = 12288 + (wc*64 + fc*16 + (lane & 15))*32 + ((lane >> 4) << 3);
      short8 bh = *(const short8*)&lds[cb];
      short8 bm = *(const short8*)&lds[cb + 4096];
      short8 bl = *(const short8*)&lds[cb + 8192];
      #pragma unroll
      for (int fr = 0; fr < 4; fr++) {
        floatx4 c = acc[fr][fc];
        c = __builtin_amdgcn_mfma_f32_16x16x32_bf16(A[0][fr], bh, c, 0, 0, 0);
        c = __builtin_amdgcn_mfma_f32_16x16x32_bf16(A[0][fr], bm, c, 0, 0, 0);
        c = __builtin_amdgcn_mfma_f32_16x16x32_bf16(A[1][fr], bh, c, 0, 0, 0);
        c = __builtin_amdgcn_mfma_f32_16x16x32_bf16(A[0][fr], bl, c, 0, 0, 0);
        c = __builtin_amdgcn_mfma_f32_16x16x32_bf16(A[2][fr], bh, c, 0, 0, 0);
        c = __builtin_amdgcn_mfma_f32_16x16x32_bf16(A[1][fr], bm, c, 0, 0, 0);
        acc[fr][fc] = c;
      }
    }
  }

  // Epilogue.  C/D: col = lane&15, row = (lane>>4)*4 + j  [verified layout].
  #pragma unroll
  for (int fr = 0; fr < 4; fr++) {
    #pragma unroll
    for (int j = 0; j < 4; j++) {
      int trow = tbase + wr*64 + fr*16 + ((lane >> 4) << 2) + j;
      float s = -3.402823466e38f;
      int bi = 0;
      #pragma unroll
      for (int fc = 0; fc < 4; fc++) {
        float v = acc[fr][fc][j];
        int col = vbase + wc*64 + fc*16 + (lane & 15);
        if (v > s) { s = v; bi = col; }   // fc ascending => cols ascending
      }
      #pragma unroll
      for (int off = 1; off < 16; off <<= 1) {   // reduce over lane&15
        float s2 = __shfl_xor(s, off, 64);
        int   b2 = __shfl_xor(bi, off, 64);
        if (s2 > s || (s2 == s && b2 < bi)) { s = s2; bi = b2; }
      }
      if ((lane & 15) == 0) {
        unsigned int ub = __float_as_uint(s);
        ub = (ub & 0x80000000u) ? ~ub : (ub | 0x80000000u);  // monotone map
        unsigned long long e =
            ((unsigned long long)ub << 32) | (unsigned long long)((unsigned int)~bi);
        atomicMax(&enc[(size_t)m * NBT + trow], e);
      }
    }
  }
}

// Per-(m,b): c(j) = longest common suffix of keys[0..j-1] with the full
// string.  For symbol x: L* = max c(j) over keys[j]==x, rpos = min such j.
// Exactly equivalent to the reference SAM walk + e[state] (= min endpos).
__global__ __launch_bounds__(256) void table_kernel() {
  __shared__ int keys[NT];
  __shared__ unsigned int best[NKQK];
  const int mb = blockIdx.x;              // m*NB + b
  const int m = mb / NB, b = mb % NB;
  const int tid = threadIdx.x;
  const unsigned long long* ek = g_enc_k + (size_t)m * NBT + (size_t)b * NT;

  for (int j = tid; j < NT; j += 256)
    keys[j] = (int)~(unsigned int)(ek[j] & 0xFFFFFFFFull);
  for (int s = tid; s < NKQK; s += 256) best[s] = 0xFFFFFFFFu;
  __syncthreads();

  for (int j = tid; j < NT; j += 256) {
    int c = 0;
    while (c < j && keys[j - 1 - c] == keys[NT - 1 - c]) c++;
    unsigned int e2 = ((unsigned int)(2047 - c) << 11) | (unsigned int)j;
    atomicMin(&best[keys[j]], e2);
  }
  __syncthreads();

  for (int s = tid; s < NKQK; s += 256) {
    int ti[NTOPK], tv[NTOPK];
    #pragma unroll
    for (int k = 0; k < NTOPK; k++) { ti[k] = -1; tv[k] = 0; }
    unsigned int bv = best[s];
    if (bv != 0xFFFFFFFFu) {
      int rpos = (int)(bv & 2047u);
      int n = 0;
      for (int off = 1; off <= NTOPK; off++) {
        int idx = rpos + off;
        if (idx >= NT) break;
        int kc = keys[idx];
        if (kc != s) { ti[n] = idx; tv[n] = kc; n++; }
      }
    }
    int* pi = g_tab_idx + ((size_t)mb * NKQK + s) * NTOPK;
    int* pv = g_tab_val + ((size_t)mb * NKQK + s) * NTOPK;
    #pragma unroll
    for (int k = 0; k < NTOPK; k++) { pi[k] = ti[k]; pv[k] = tv[k]; }
  }
}

// out[b,t,:] = sum_m w[m] * sum_k Vemb[m][vcode(idx_k)] * Vemb[m][val_k]
__global__ __launch_bounds__(256) void gather_kernel(
    const float* __restrict__ Vemb, const float* __restrict__ alpha,
    float* __restrict__ out)
{
  const int token = blockIdx.x;          // b*NT + t
  const int tid = threadIdx.x;
  const int b = token >> 11;             // NT = 2048
  const int d = tid * 4;

  float a0 = alpha[0], a1 = alpha[1];
  float mx = fmaxf(a0, a1);
  float e0 = __expf(a0 - mx), e1 = __expf(a1 - mx);
  float inv = 1.0f / (e0 + e1);
  float w[2] = {e0 * inv, e1 * inv};

  float4 acc = make_float4(0.f, 0.f, 0.f, 0.f);
  #pragma unroll
  for (int m = 0; m < NROUTE; m++) {
    int xq = (int)~(unsigned int)(g_enc_q[(size_t)m * NBT + token] & 0xFFFFFFFFull);
    const int mb = m * NB + b;
    const int* pi = g_tab_idx + ((size_t)mb * NKQK + xq) * NTOPK;
    const int* pv = g_tab_val + ((size_t)mb * NKQK + xq) * NTOPK;
    const float* Ve = Vemb + (size_t)m * (NVV + 1) * ND;
    float4 am = make_float4(0.f, 0.f, 0.f, 0.f);
    for (int k = 0; k < NTOPK; k++) {
      int idx = pi[k];
      if (idx < 0) break;
      int val = pv[k];
      int vcode = (int)~(unsigned int)(
          g_enc_v[(size_t)m * NBT + (size_t)b * NT + idx] & 0xFFFFFFFFull);
      float4 g = *(const float4*)(Ve + (size_t)vcode * ND + d);
      float4 l = *(const float4*)(Ve + (size_t)val * ND + d);
      am.x += g.x * l.x; am.y += g.y * l.y;
      am.z += g.z * l.z; am.w += g.w * l.w;
    }
    acc.x += w[m] * am.x; acc.y += w[m] * am.y;
    acc.z += w[m] * am.z; acc.w += w[m] * am.w;
  }
  *(float4*)(out + (size_t)token * ND + d) = acc;
}

extern "C" void kernel_launch(void* const* d_in, const int* in_sizes, int n_in,
                              void* d_out, int out_size, void* d_ws, size_t ws_size,
                              hipStream_t stream) {
  const float* x     = (const float*)d_in[0];
  const float* Wq    = (const float*)d_in[1];
  const float* Wk    = (const float*)d_in[2];
  const float* Wv    = (const float*)d_in[3];
  const float* Vemb  = (const float*)d_in[4];
  const float* alpha = (const float*)d_in[5];
  float* out = (float*)d_out;
  (void)in_sizes; (void)n_in; (void)out_size; (void)d_ws; (void)ws_size;

  zero_enc_kernel<<<(NROUTE*NBT + 255) / 256, 256, 0, stream>>>();

  split_kernel<<<2048, 256, 0, stream>>>(x,  0, NBT*ND/4);
  split_kernel<<<1024, 256, 0, stream>>>(Wq, 1, NROUTE*NKQK*ND/4);
  split_kernel<<<1024, 256, 0, stream>>>(Wk, 2, NROUTE*NKQK*ND/4);
  split_kernel<<<2048, 256, 0, stream>>>(Wv, 3, NROUTE*NVV*ND/4);

  dim3 gq(NBT/128, NKQK/128, NROUTE);   // 64 x 4 x 2
  dim3 gv(NBT/128, NVV/128, NROUTE);    // 64 x 64 x 2
  mfma_argmax_kernel<<<gq, 256, 0, stream>>>(NKQK, 0);
  mfma_argmax_kernel<<<gq, 256, 0, stream>>>(NKQK, 1);
  mfma_argmax_kernel<<<gv, 256, 0, stream>>>(NVV, 2);

  table_kernel<<<NROUTE * NB, 256, 0, stream>>>();
  gather_kernel<<<NBT, 256, 0, stream>>>(Vemb, alpha, out);
}

// Round 6
// 2134.976 us; speedup vs baseline: 3.0124x; 3.0124x over previous
//
#include <hip/hip_runtime.h>
#include <stdint.h>

// Problem constants (fixed by the reference)
#define NROUTE 2
#define NB 4
#define NT 2048
#define ND 1024
#define NKQK 512
#define NVV 8192
#define NTOPK 8
#define NBT (NB*NT)   // 8192 tokens

typedef short short8 __attribute__((ext_vector_type(8)));
typedef float floatx4 __attribute__((ext_vector_type(4)));

// Persistent device scratch (module-scope; fully rewritten every call).
__device__ unsigned long long g_enc_q[NROUTE*NBT];
__device__ unsigned long long g_enc_k[NROUTE*NBT];
__device__ unsigned long long g_enc_v[NROUTE*NBT];
__device__ int g_tab_idx[NROUTE*NB*NKQK*NTOPK];
__device__ int g_tab_val[NROUTE*NB*NKQK*NTOPK];

// bf16 triple-split of inputs: value = h + m + l (each RNE bf16).
__device__ unsigned short g_xh[NBT*ND],        g_xm[NBT*ND],        g_xl[NBT*ND];
__device__ unsigned short g_wqh[NROUTE*NKQK*ND], g_wqm[NROUTE*NKQK*ND], g_wql[NROUTE*NKQK*ND];
__device__ unsigned short g_wkh[NROUTE*NKQK*ND], g_wkm[NROUTE*NKQK*ND], g_wkl[NROUTE*NKQK*ND];
__device__ unsigned short g_wvh[NROUTE*NVV*ND],  g_wvm[NROUTE*NVV*ND],  g_wvl[NROUTE*NVV*ND];

__global__ __launch_bounds__(256) void zero_enc_kernel() {
  int i = blockIdx.x * 256 + threadIdx.x;
  if (i < NROUTE*NBT) { g_enc_q[i] = 0ull; g_enc_k[i] = 0ull; g_enc_v[i] = 0ull; }
}

__device__ __forceinline__ unsigned short rne_bf16(float f) {
  unsigned u = __float_as_uint(f);
  return (unsigned short)((u + 0x7FFFu + ((u >> 16) & 1u)) >> 16);
}

// which: 0=x, 1=Wq, 2=Wk, 3=Wv.  n4 = element_count/4.
// x = h + m + l with h=RNE(x), m=RNE(x-h), l=RNE(x-h-m); both residual
// subtractions are exact (Sterbenz), dropped tail <= 2^-26 relative.
__global__ __launch_bounds__(256) void split_kernel(
    const float* __restrict__ src, int which, int n4)
{
  unsigned short* __restrict__ h = (which==0)?g_xh:(which==1)?g_wqh:(which==2)?g_wkh:g_wvh;
  unsigned short* __restrict__ m = (which==0)?g_xm:(which==1)?g_wqm:(which==2)?g_wkm:g_wvm;
  unsigned short* __restrict__ l = (which==0)?g_xl:(which==1)?g_wql:(which==2)?g_wkl:g_wvl;
  int stride = gridDim.x * 256;
  for (int i = blockIdx.x * 256 + threadIdx.x; i < n4; i += stride) {
    float4 v = ((const float4*)src)[i];
    float vv[4] = {v.x, v.y, v.z, v.w};
    unsigned short hb[4], mb[4], lb[4];
    #pragma unroll
    for (int j = 0; j < 4; j++) {
      float x = vv[j];
      unsigned short hh = rne_bf16(x);
      float hf = __uint_as_float((unsigned)hh << 16);
      float r1 = x - hf;
      unsigned short mm = rne_bf16(r1);
      float mf = __uint_as_float((unsigned)mm << 16);
      float r2 = r1 - mf;
      hb[j] = hh; mb[j] = mm; lb[j] = rne_bf16(r2);
    }
    ((ushort4*)h)[i] = make_ushort4(hb[0], hb[1], hb[2], hb[3]);
    ((ushort4*)m)[i] = make_ushort4(mb[0], mb[1], mb[2], mb[3]);
    ((ushort4*)l)[i] = make_ushort4(lb[0], lb[1], lb[2], lb[3]);
  }
}

// Stage 16B: global (per-lane address) -> LDS (wave-uniform base; HW adds
// lane*16).  No VGPR round-trip, no data registers held.
__device__ __forceinline__ void stage16(const unsigned short* g,
                                        unsigned short* l, int lane) {
#if __has_builtin(__builtin_amdgcn_global_load_lds)
  __builtin_amdgcn_global_load_lds(
      (const __attribute__((address_space(1))) void*)g,
      (__attribute__((address_space(3))) void*)l, 16, 0, 0);
#else
  *(uint4*)(l + lane * 8) = *(const uint4*)g;   // fallback (reg round-trip)
#endif
}

// MFMA GEMM + argmax.  scores[token][v] = sum_d x[t][d]*W[v][d], computed as
// 6 bf16 MFMA products (hh,hm,mh,hl,lh,mm) in fp32 accumulators.
// 128x128 tile, BK=32, 4 waves (2x2), wave = 64x64 via 4x4 16x16x32 frags.
// LDS 48KB, 6 regions of 8KB: A h/m/l at ushort base L*4096, B at
// 12288+L*4096; region layout [row 0..127][k 0..31] (row = 32 ushorts).
// Staging: 48 x 1KB chunks; wave w stages subchunks {2w,2w+1} of every
// region via global_load_lds dwordx4 (lane l -> row l/4, kword l%4 --
// exactly the linear lane order the DMA writes; LDS image bit-identical
// to the round-3 verified register-staged layout).
// Cross-block argmax merge via 64-bit atomicMax of monotone encoding
// (score_bits<<32)|~idx  (max score, then smallest index on ties).
__global__ __launch_bounds__(256) void mfma_argmax_kernel(int V, int sel)
{
  __shared__ unsigned short lds[24576];   // 48 KB
  unsigned long long* enc = (sel==0)?g_enc_q:(sel==1)?g_enc_k:g_enc_v;
  const unsigned short* __restrict__ Bh = (sel==0)?g_wqh:(sel==1)?g_wkh:g_wvh;
  const unsigned short* __restrict__ Bm = (sel==0)?g_wqm:(sel==1)?g_wkm:g_wvm;
  const unsigned short* __restrict__ Bl = (sel==0)?g_wql:(sel==1)?g_wkl:g_wvl;

  const int m     = blockIdx.z;
  const int tbase = blockIdx.x * 128;
  const int vbase = blockIdx.y * 128;
  const int tid   = threadIdx.x;
  const int lane  = tid & 63;
  const int wid   = tid >> 6;
  const int wr    = wid >> 1, wc = wid & 1;

  // staging addressing: wave wid stages subchunks s0=2*wid, s1=2*wid+1
  const int srow = lane >> 2;            // chunk-relative row 0..15
  const int skof = (lane & 3) << 3;      // ushort k-offset 0,8,16,24
  const int s0 = wid << 1;
  const int offA0 = (tbase + s0*16 + srow) * ND + skof;   // + 16*ND for s1
  const int offB0 = (m*V + vbase + s0*16 + srow) * ND + skof;
  const int uA0 = s0*512, uA1 = uA0 + 512;                // LDS ushort bases
  const int uB0 = 12288 + s0*512, uB1 = uB0 + 512;

  // fragment read bases (ushort offsets; 16B aligned)
  const int abase = (wr*64 + (lane & 15))*32 + ((lane >> 4) << 3);
  const int bbase = 12288 + (wc*64 + (lane & 15))*32 + ((lane >> 4) << 3);

  floatx4 acc[4][4];
  #pragma unroll
  for (int i = 0; i < 4; i++)
    #pragma unroll
    for (int j = 0; j < 4; j++) acc[i][j] = (floatx4){0.f, 0.f, 0.f, 0.f};

  for (int kt = 0; kt < ND/32; kt++) {
    const int k0 = kt * 32;
    __syncthreads();                     // prev tile fully consumed (lgkm)
    stage16(g_xh + offA0 + k0,         lds + uA0,        lane);
    stage16(g_xh + offA0 + 16*ND + k0, lds + uA1,        lane);
    stage16(g_xm + offA0 + k0,         lds + 4096 + uA0, lane);
    stage16(g_xm + offA0 + 16*ND + k0, lds + 4096 + uA1, lane);
    stage16(g_xl + offA0 + k0,         lds + 8192 + uA0, lane);
    stage16(g_xl + offA0 + 16*ND + k0, lds + 8192 + uA1, lane);
    stage16(Bh + offB0 + k0,           lds + uB0,        lane);
    stage16(Bh + offB0 + 16*ND + k0,   lds + uB1,        lane);
    stage16(Bm + offB0 + k0,           lds + 4096 + uB0, lane);
    stage16(Bm + offB0 + 16*ND + k0,   lds + 4096 + uB1, lane);
    stage16(Bl + offB0 + k0,           lds + 8192 + uB0, lane);
    stage16(Bl + offB0 + 16*ND + k0,   lds + 8192 + uB1, lane);
    __syncthreads();                     // drains vmcnt -> tile visible

    short8 A[3][4];
    #pragma unroll
    for (int L = 0; L < 3; L++)
      #pragma unroll
      for (int fr = 0; fr < 4; fr++)
        A[L][fr] = *(const short8*)&lds[abase + L*4096 + fr*512];

    #pragma unroll
    for (int fc = 0; fc < 4; fc++) {
      short8 bh = *(const short8*)&lds[bbase + fc*512];
      short8 bm = *(const short8*)&lds[bbase + 4096 + fc*512];
      short8 bl = *(const short8*)&lds[bbase + 8192 + fc*512];
      #pragma unroll
      for (int fr = 0; fr < 4; fr++) {
        floatx4 c = acc[fr][fc];
        c = __builtin_amdgcn_mfma_f32_16x16x32_bf16(A[0][fr], bh, c, 0, 0, 0);
        c = __builtin_amdgcn_mfma_f32_16x16x32_bf16(A[0][fr], bm, c, 0, 0, 0);
        c = __builtin_amdgcn_mfma_f32_16x16x32_bf16(A[1][fr], bh, c, 0, 0, 0);
        c = __builtin_amdgcn_mfma_f32_16x16x32_bf16(A[0][fr], bl, c, 0, 0, 0);
        c = __builtin_amdgcn_mfma_f32_16x16x32_bf16(A[2][fr], bh, c, 0, 0, 0);
        c = __builtin_amdgcn_mfma_f32_16x16x32_bf16(A[1][fr], bm, c, 0, 0, 0);
        acc[fr][fc] = c;
      }
    }
  }

  // Epilogue.  C/D: col = lane&15, row = (lane>>4)*4 + j  [verified layout].
  #pragma unroll
  for (int fr = 0; fr < 4; fr++) {
    #pragma unroll
    for (int j = 0; j < 4; j++) {
      int trow = tbase + wr*64 + fr*16 + ((lane >> 4) << 2) + j;
      float s = -3.402823466e38f;
      int bi = 0;
      #pragma unroll
      for (int fc = 0; fc < 4; fc++) {
        float v = acc[fr][fc][j];
        int col = vbase + wc*64 + fc*16 + (lane & 15);
        if (v > s) { s = v; bi = col; }   // fc ascending => cols ascending
      }
      #pragma unroll
      for (int off = 1; off < 16; off <<= 1) {   // reduce over lane&15
        float s2 = __shfl_xor(s, off, 64);
        int   b2 = __shfl_xor(bi, off, 64);
        if (s2 > s || (s2 == s && b2 < bi)) { s = s2; bi = b2; }
      }
      if ((lane & 15) == 0) {
        unsigned int ub = __float_as_uint(s);
        ub = (ub & 0x80000000u) ? ~ub : (ub | 0x80000000u);  // monotone map
        unsigned long long e =
            ((unsigned long long)ub << 32) | (unsigned long long)((unsigned int)~bi);
        atomicMax(&enc[(size_t)m * NBT + trow], e);
      }
    }
  }
}

// Per-(m,b): c(j) = longest common suffix of keys[0..j-1] with the full
// string.  For symbol x: L* = max c(j) over keys[j]==x, rpos = min such j.
// Exactly equivalent to the reference SAM walk + e[state] (= min endpos).
__global__ __launch_bounds__(256) void table_kernel() {
  __shared__ int keys[NT];
  __shared__ unsigned int best[NKQK];
  const int mb = blockIdx.x;              // m*NB + b
  const int m = mb / NB, b = mb % NB;
  const int tid = threadIdx.x;
  const unsigned long long* ek = g_enc_k + (size_t)m * NBT + (size_t)b * NT;

  for (int j = tid; j < NT; j += 256)
    keys[j] = (int)~(unsigned int)(ek[j] & 0xFFFFFFFFull);
  for (int s = tid; s < NKQK; s += 256) best[s] = 0xFFFFFFFFu;
  __syncthreads();

  for (int j = tid; j < NT; j += 256) {
    int c = 0;
    while (c < j && keys[j - 1 - c] == keys[NT - 1 - c]) c++;
    unsigned int e2 = ((unsigned int)(2047 - c) << 11) | (unsigned int)j;
    atomicMin(&best[keys[j]], e2);
  }
  __syncthreads();

  for (int s = tid; s < NKQK; s += 256) {
    int ti[NTOPK], tv[NTOPK];
    #pragma unroll
    for (int k = 0; k < NTOPK; k++) { ti[k] = -1; tv[k] = 0; }
    unsigned int bv = best[s];
    if (bv != 0xFFFFFFFFu) {
      int rpos = (int)(bv & 2047u);
      int n = 0;
      for (int off = 1; off <= NTOPK; off++) {
        int idx = rpos + off;
        if (idx >= NT) break;
        int kc = keys[idx];
        if (kc != s) { ti[n] = idx; tv[n] = kc; n++; }
      }
    }
    int* pi = g_tab_idx + ((size_t)mb * NKQK + s) * NTOPK;
    int* pv = g_tab_val + ((size_t)mb * NKQK + s) * NTOPK;
    #pragma unroll
    for (int k = 0; k < NTOPK; k++) { pi[k] = ti[k]; pv[k] = tv[k]; }
  }
}

// out[b,t,:] = sum_m w[m] * sum_k Vemb[m][vcode(idx_k)] * Vemb[m][val_k]
__global__ __launch_bounds__(256) void gather_kernel(
    const float* __restrict__ Vemb, const float* __restrict__ alpha,
    float* __restrict__ out)
{
  const int token = blockIdx.x;          // b*NT + t
  const int tid = threadIdx.x;
  const int b = token >> 11;             // NT = 2048
  const int d = tid * 4;

  float a0 = alpha[0], a1 = alpha[1];
  float mx = fmaxf(a0, a1);
  float e0 = __expf(a0 - mx), e1 = __expf(a1 - mx);
  float inv = 1.0f / (e0 + e1);
  float w[2] = {e0 * inv, e1 * inv};

  float4 acc = make_float4(0.f, 0.f, 0.f, 0.f);
  #pragma unroll
  for (int m = 0; m < NROUTE; m++) {
    int xq = (int)~(unsigned int)(g_enc_q[(size_t)m * NBT + token] & 0xFFFFFFFFull);
    const int mb = m * NB + b;
    const int* pi = g_tab_idx + ((size_t)mb * NKQK + xq) * NTOPK;
    const int* pv = g_tab_val + ((size_t)mb * NKQK + xq) * NTOPK;
    const float* Ve = Vemb + (size_t)m * (NVV + 1) * ND;
    float4 am = make_float4(0.f, 0.f, 0.f, 0.f);
    for (int k = 0; k < NTOPK; k++) {
      int idx = pi[k];
      if (idx < 0) break;
      int val = pv[k];
      int vcode = (int)~(unsigned int)(
          g_enc_v[(size_t)m * NBT + (size_t)b * NT + idx] & 0xFFFFFFFFull);
      float4 g = *(const float4*)(Ve + (size_t)vcode * ND + d);
      float4 l = *(const float4*)(Ve + (size_t)val * ND + d);
      am.x += g.x * l.x; am.y += g.y * l.y;
      am.z += g.z * l.z; am.w += g.w * l.w;
    }
    acc.x += w[m] * am.x; acc.y += w[m] * am.y;
    acc.z += w[m] * am.z; acc.w += w[m] * am.w;
  }
  *(float4*)(out + (size_t)token * ND + d) = acc;
}

extern "C" void kernel_launch(void* const* d_in, const int* in_sizes, int n_in,
                              void* d_out, int out_size, void* d_ws, size_t ws_size,
                              hipStream_t stream) {
  const float* x     = (const float*)d_in[0];
  const float* Wq    = (const float*)d_in[1];
  const float* Wk    = (const float*)d_in[2];
  const float* Wv    = (const float*)d_in[3];
  const float* Vemb  = (const float*)d_in[4];
  const float* alpha = (const float*)d_in[5];
  float* out = (float*)d_out;
  (void)in_sizes; (void)n_in; (void)out_size; (void)d_ws; (void)ws_size;

  zero_enc_kernel<<<(NROUTE*NBT + 255) / 256, 256, 0, stream>>>();

  split_kernel<<<2048, 256, 0, stream>>>(x,  0, NBT*ND/4);
  split_kernel<<<1024, 256, 0, stream>>>(Wq, 1, NROUTE*NKQK*ND/4);
  split_kernel<<<1024, 256, 0, stream>>>(Wk, 2, NROUTE*NKQK*ND/4);
  split_kernel<<<2048, 256, 0, stream>>>(Wv, 3, NROUTE*NVV*ND/4);

  dim3 gq(NBT/128, NKQK/128, NROUTE);   // 64 x 4 x 2
  dim3 gv(NBT/128, NVV/128, NROUTE);    // 64 x 64 x 2
  mfma_argmax_kernel<<<gq, 256, 0, stream>>>(NKQK, 0);
  mfma_argmax_kernel<<<gq, 256, 0, stream>>>(NKQK, 1);
  mfma_argmax_kernel<<<gv, 256, 0, stream>>>(NVV, 2);

  table_kernel<<<NROUTE * NB, 256, 0, stream>>>();
  gather_kernel<<<NBT, 256, 0, stream>>>(Vemb, alpha, out);
}